// Round 3
// baseline (341.190 us; speedup 1.0000x reference)
//
#include <hip/hip_runtime.h>

// 2D Haar DWT, single fused pass, dense-load variant.
// x: (BC, 1024, 1024) fp32 -> out: [LL | LH | HL | HH], each (BC, 512, 512) fp32.
// Per output pixel (i,j):
//   a=x[2i-1,2j-1] b=x[2i-1,2j] c=x[2i,2j-1] d=x[2i,2j]   (index -1 => 0)
//   LL=0.5(a+b+c+d) LH=0.5(c+d-a-b) HL=0.5((b-a)+(d-c)) HH=0.5((d-c)-(b-a))
//
// One block (256 threads) per output row. Thread t loads input cols 4t..4t+3
// of rows {2i-1, 2i} as ONE dense float4 per row (16B/lane, fully dense per
// wave instruction). The -1 boundary element comes from the previous lane via
// __shfl_up; only lane 0 of each wave falls back to a (L1-hit) scalar load.
// Outputs: 2 cols per subband per thread, nontemporal float2 stores (streamed,
// no reuse -> keep them out of L2's way). Native clang vector type for the
// nontemporal builtin (HIP float2 is a class and is rejected).

typedef float v2f __attribute__((ext_vector_type(2)));

__global__ __launch_bounds__(256) void dwt_haar_kernel(
    const float* __restrict__ x, float* __restrict__ out, int n_bc)
{
    const int i    = blockIdx.x & 511;   // output row
    const int bc   = blockIdx.x >> 9;    // image plane
    const int t    = threadIdx.x;        // 0..255 -> input cols 4t..4t+3
    const int lane = t & 63;
    const int c0   = t << 2;

    const long long S = (long long)n_bc * 512 * 512;   // subband size (elements)

    const float* rbot = x + (((long long)bc << 10) + 2 * i) * 1024; // row 2i

    // row 2i (always valid)
    float4 vb = *(const float4*)(rbot + c0);
    float  pb = __shfl_up(vb.w, 1);                    // col 4t-1 from lane-1
    if (lane == 0) pb = (t > 0) ? rbot[c0 - 1] : 0.0f; // wave seam / zero-pad

    // row 2i-1 (zero row for i==0; branch is block-uniform)
    float4 vt;
    float  pt;
    if (i > 0) {
        const float* rtop = rbot - 1024;
        vt = *(const float4*)(rtop + c0);
        pt = __shfl_up(vt.w, 1);
        if (lane == 0) pt = (t > 0) ? rtop[c0 - 1] : 0.0f;
    } else {
        vt = make_float4(0.0f, 0.0f, 0.0f, 0.0f);
        pt = 0.0f;
    }

    // output col 2t   : a=pt,   b=vt.x, c=pb,   d=vb.x
    // output col 2t+1 : a=vt.y, b=vt.z, c=vb.y, d=vb.z
    v2f llv, lhv, hlv, hhv;
    {
        float st = pt + vt.x, dt = vt.x - pt;
        float sb = pb + vb.x, db = vb.x - pb;
        llv.x = 0.5f * (st + sb);
        lhv.x = 0.5f * (sb - st);
        hlv.x = 0.5f * (dt + db);
        hhv.x = 0.5f * (db - dt);
    }
    {
        float st = vt.y + vt.z, dt = vt.z - vt.y;
        float sb = vb.y + vb.z, db = vb.z - vb.y;
        llv.y = 0.5f * (st + sb);
        lhv.y = 0.5f * (sb - st);
        hlv.y = 0.5f * (dt + db);
        hhv.y = 0.5f * (db - dt);
    }

    const long long obase = (((long long)bc << 9) + i) * 512 + (t << 1);
    __builtin_nontemporal_store(llv, (v2f*)(out +         obase));
    __builtin_nontemporal_store(lhv, (v2f*)(out +     S + obase));
    __builtin_nontemporal_store(hlv, (v2f*)(out + 2 * S + obase));
    __builtin_nontemporal_store(hhv, (v2f*)(out + 3 * S + obase));
}

extern "C" void kernel_launch(void* const* d_in, const int* in_sizes, int n_in,
                              void* d_out, int out_size, void* d_ws, size_t ws_size,
                              hipStream_t stream) {
    const float* x = (const float*)d_in[0];
    float* out = (float*)d_out;

    const int n_bc   = in_sizes[0] / (1024 * 1024);  // B*C = 48
    const int blocks = n_bc * 512;                   // one block per output row

    dwt_haar_kernel<<<blocks, 256, 0, stream>>>(x, out, n_bc);
}